// Round 2
// baseline (236.106 us; speedup 1.0000x reference)
//
#include <hip/hip_runtime.h>

// GAT layer: B=8, N=2048, Fin=Fout=64
// k01: blocks 0..255   = k1: Wh=h@W (MFMA bf16 -> WhT[b][o][n]) + s,t fp32 via Wa=W@a
//      blocks 256..1279 = k0: pack adj!=0 into bitmask (134 MB -> 4 MB), pure HBM stream
// k2 : flash-style masked softmax + P@Wh; mask preloaded to VGPRs -> no HBM in j-loop.

#define ALPHA 0.2f

typedef __attribute__((ext_vector_type(8))) short  short8;
typedef __attribute__((ext_vector_type(4))) float  f32x4;

static __device__ __forceinline__ unsigned short f2bf(float f) {
    unsigned u = __builtin_bit_cast(unsigned, f);
    u += 0x7fffu + ((u >> 16) & 1u);   // round-to-nearest-even
    return (unsigned short)(u >> 16);
}

// two f32 -> packed bf16x2 (round-half-up via +0x8000, then v_perm grabs high halves)
static __device__ __forceinline__ unsigned pack_bf2(float lo, float hi) {
    unsigned ulo = __builtin_bit_cast(unsigned, lo) + 0x8000u;
    unsigned uhi = __builtin_bit_cast(unsigned, hi) + 0x8000u;
    return __builtin_amdgcn_perm(uhi, ulo, 0x07060302);
}

// ---------------- k01 ----------------
__global__ __launch_bounds__(256) void k01(
    const float* __restrict__ h, const int* __restrict__ adj,
    const float* __restrict__ W, const float* __restrict__ a,
    unsigned short* __restrict__ whT, float* __restrict__ sw,
    float* __restrict__ tw, unsigned* __restrict__ mask)
{
    __shared__ float W_l[64 * 65];
    __shared__ float wa[128];
    __shared__ float tile[4 * 16 * 65];

    const int tid = threadIdx.x;

    if (blockIdx.x >= 256) {
        // ---- k0: adj -> bitmask, pure stream ----
        const int mb = blockIdx.x - 256;          // 0..1023
        const int4* a4 = (const int4*)adj;        // 8.388608M int4 total = 1024*8192
        #pragma unroll 1
        for (int batch = 0; batch < 4; ++batch) {
            const size_t base = (size_t)mb * 8192 + batch * 2048 + tid;
            int4 v[8];
            #pragma unroll
            for (int it = 0; it < 8; ++it) v[it] = a4[base + it * 256];
            #pragma unroll
            for (int it = 0; it < 8; ++it) {
                unsigned nib = (v[it].x != 0 ? 1u : 0u) | (v[it].y != 0 ? 2u : 0u)
                             | (v[it].z != 0 ? 4u : 0u) | (v[it].w != 0 ? 8u : 0u);
                unsigned w = nib << ((tid & 7) * 4);
                w |= __shfl_xor(w, 1, 64);
                w |= __shfl_xor(w, 2, 64);
                w |= __shfl_xor(w, 4, 64);
                if ((tid & 7) == 0) mask[(base + it * 256) >> 3] = w;
            }
        }
        return;
    }

    // ---- k1: Wh + s,t ----
    const int lane = tid & 63, wv = tid >> 6;
    const int im   = lane & 15, kq = lane >> 4;

    #pragma unroll
    for (int k = 0; k < 16; ++k) {
        int e = tid + 256 * k;
        W_l[(e >> 6) * 65 + (e & 63)] = W[e];
    }
    __syncthreads();

    if (tid < 128) {
        int f = tid & 63;
        const float* ap = a + (tid >> 6) * 64;
        float acc = 0.f;
        #pragma unroll 8
        for (int o = 0; o < 64; ++o) acc += W_l[f * 65 + o] * ap[o];
        wa[tid] = acc;
    }
    __syncthreads();

    short8 bf[4][2];
    #pragma unroll
    for (int nb = 0; nb < 4; ++nb)
        #pragma unroll
        for (int ks = 0; ks < 2; ++ks)
            #pragma unroll
            for (int u = 0; u < 8; ++u)
                bf[nb][ks][u] = (short)f2bf(W_l[(ks * 32 + kq * 8 + u) * 65 + nb * 16 + im]);

    const int row0 = blockIdx.x * 64 + wv * 16;
    const int bb = row0 >> 11, n_base = row0 & 2047;
    const float* hrow = h + (size_t)(row0 + im) * 64;

    float hv[2][8];
    short8 af[2];
    float sp = 0.f, tp = 0.f;
    #pragma unroll
    for (int ks = 0; ks < 2; ++ks) {
        float4 A = *(const float4*)(hrow + ks * 32 + kq * 8);
        float4 Bv = *(const float4*)(hrow + ks * 32 + kq * 8 + 4);
        hv[ks][0] = A.x;  hv[ks][1] = A.y;  hv[ks][2] = A.z;  hv[ks][3] = A.w;
        hv[ks][4] = Bv.x; hv[ks][5] = Bv.y; hv[ks][6] = Bv.z; hv[ks][7] = Bv.w;
        #pragma unroll
        for (int u = 0; u < 8; ++u) {
            int f = ks * 32 + kq * 8 + u;
            sp += hv[ks][u] * wa[f];
            tp += hv[ks][u] * wa[64 + f];
            af[ks][u] = (short)f2bf(hv[ks][u]);
        }
    }
    sp += __shfl_xor(sp, 16, 64); sp += __shfl_xor(sp, 32, 64);
    tp += __shfl_xor(tp, 16, 64); tp += __shfl_xor(tp, 32, 64);
    if (lane < 16) {
        sw[row0 + lane] = sp;
        tw[row0 + lane] = tp;
    }

    f32x4 acc[4] = {{0.f,0.f,0.f,0.f},{0.f,0.f,0.f,0.f},{0.f,0.f,0.f,0.f},{0.f,0.f,0.f,0.f}};
    #pragma unroll
    for (int ks = 0; ks < 2; ++ks)
        #pragma unroll
        for (int nb = 0; nb < 4; ++nb)
            acc[nb] = __builtin_amdgcn_mfma_f32_16x16x32_bf16(af[ks], bf[nb][ks], acc[nb], 0, 0, 0);

    #pragma unroll
    for (int nb = 0; nb < 4; ++nb)
        #pragma unroll
        for (int r = 0; r < 4; ++r)
            tile[wv * 1040 + (kq * 4 + r) * 65 + nb * 16 + im] = acc[nb][r];
    __syncthreads();

    #pragma unroll
    for (int k = 0; k < 16; ++k) {
        int o = kq + 4 * k;
        float v = tile[wv * 1040 + im * 65 + o];
        whT[(size_t)(bb * 64 + o) * 2048 + n_base + im] = f2bf(v);
    }
}

// ---------------- k2: masked softmax + P@Wh ----------------
// grid 1024 blocks (b, i0) x 256 thr; wave = contiguous 512-j stripe; no HBM in j-loop.
__global__ __launch_bounds__(256, 4) void k2_attn(
    const unsigned* __restrict__ mask, const unsigned short* __restrict__ whT,
    const float* __restrict__ sw, const float* __restrict__ tw,
    float* __restrict__ out)
{
    __shared__ float t_l[2048];
    __shared__ float cpart[4 * 1040];
    __shared__ float zp[64];

    const int tid  = threadIdx.x;
    const int lane = tid & 63, wv = tid >> 6;
    const int im   = lane & 15, kq = lane >> 4;
    const int b    = blockIdx.x >> 7;
    const int i0   = (blockIdx.x & 127) << 4;

    // stage t row -> LDS
    {
        const float4* tp4 = (const float4*)(tw + (size_t)b * 2048);
        *(float4*)&t_l[tid * 4]         = tp4[tid];
        *(float4*)&t_l[(tid + 256) * 4] = tp4[tid + 256];
    }

    // preload this lane's 16 mask words (row i0+im, j in [wv*512, wv*512+512))
    const unsigned* mrow = mask + (size_t)(b * 2048 + i0 + im) * 64 + wv * 16;
    uint4 m0 = *(const uint4*)mrow,        m1 = *(const uint4*)(mrow + 4);
    uint4 m2 = *(const uint4*)(mrow + 8),  m3 = *(const uint4*)(mrow + 12);
    unsigned mm[16] = {m0.x, m0.y, m0.z, m0.w, m1.x, m1.y, m1.z, m1.w,
                       m2.x, m2.y, m2.z, m2.w, m3.x, m3.y, m3.z, m3.w};

    const float sl = sw[b * 2048 + i0 + im];
    const int j00 = wv * 512 + kq * 8;
    const unsigned short* whp0 = whT + ((size_t)(b * 64 +  0 + im) * 2048 + j00);
    const unsigned short* whp1 = whT + ((size_t)(b * 64 + 16 + im) * 2048 + j00);
    const unsigned short* whp2 = whT + ((size_t)(b * 64 + 32 + im) * 2048 + j00);
    const unsigned short* whp3 = whT + ((size_t)(b * 64 + 48 + im) * 2048 + j00);
    const int tbase = wv * 512 + kq * 8;

    __syncthreads();

    f32x4 acc0 = {0.f,0.f,0.f,0.f}, acc1 = {0.f,0.f,0.f,0.f};
    f32x4 acc2 = {0.f,0.f,0.f,0.f}, acc3 = {0.f,0.f,0.f,0.f};
    float zs = 0.f;

    short8 w0 = *(const short8*)(const void*)whp0;
    short8 w1 = *(const short8*)(const void*)whp1;
    short8 w2 = *(const short8*)(const void*)whp2;
    short8 w3 = *(const short8*)(const void*)whp3;

    #pragma unroll
    for (int s = 0; s < 16; ++s) {
        short8 n0 = w0, n1 = w1, n2 = w2, n3 = w3;
        if (s < 15) {
            n0 = *(const short8*)(const void*)(whp0 + (s + 1) * 32);
            n1 = *(const short8*)(const void*)(whp1 + (s + 1) * 32);
            n2 = *(const short8*)(const void*)(whp2 + (s + 1) * 32);
            n3 = *(const short8*)(const void*)(whp3 + (s + 1) * 32);
        }

        float4 tA = *(const float4*)&t_l[tbase + s * 32];
        float4 tB = *(const float4*)&t_l[tbase + s * 32 + 4];
        const unsigned mbyte = (mm[s] >> (kq * 8)) & 0xffu;

        float tv[8] = {tA.x, tA.y, tA.z, tA.w, tB.x, tB.y, tB.z, tB.w};
        float p[8];
        #pragma unroll
        for (int u = 0; u < 8; ++u) {
            float e = sl + tv[u];
            e = fmaxf(e, ALPHA * e);                 // leakyrelu
            float w = __expf(e);
            p[u] = (mbyte & (1u << u)) ? w : 0.f;
            zs += p[u];
        }

        int4 ai;
        ai.x = (int)pack_bf2(p[0], p[1]);
        ai.y = (int)pack_bf2(p[2], p[3]);
        ai.z = (int)pack_bf2(p[4], p[5]);
        ai.w = (int)pack_bf2(p[6], p[7]);
        short8 af = __builtin_bit_cast(short8, ai);

        acc0 = __builtin_amdgcn_mfma_f32_16x16x32_bf16(af, w0, acc0, 0, 0, 0);
        acc1 = __builtin_amdgcn_mfma_f32_16x16x32_bf16(af, w1, acc1, 0, 0, 0);
        acc2 = __builtin_amdgcn_mfma_f32_16x16x32_bf16(af, w2, acc2, 0, 0, 0);
        acc3 = __builtin_amdgcn_mfma_f32_16x16x32_bf16(af, w3, acc3, 0, 0, 0);

        w0 = n0; w1 = n1; w2 = n2; w3 = n3;
    }

    zs += __shfl_xor(zs, 16, 64);
    zs += __shfl_xor(zs, 32, 64);
    if (lane < 16) zp[wv * 16 + lane] = zs;

    #pragma unroll
    for (int r = 0; r < 4; ++r) {
        cpart[wv * 1040 + (kq * 4 + r) * 65 +  0 + im] = acc0[r];
        cpart[wv * 1040 + (kq * 4 + r) * 65 + 16 + im] = acc1[r];
        cpart[wv * 1040 + (kq * 4 + r) * 65 + 32 + im] = acc2[r];
        cpart[wv * 1040 + (kq * 4 + r) * 65 + 48 + im] = acc3[r];
    }
    __syncthreads();

    #pragma unroll
    for (int k = 0; k < 4; ++k) {
        int idx = tid + 256 * k;
        int i = idx >> 6, o = idx & 63;
        float ssum = cpart[0 * 1040 + i * 65 + o] + cpart[1 * 1040 + i * 65 + o]
                   + cpart[2 * 1040 + i * 65 + o] + cpart[3 * 1040 + i * 65 + o];
        float z = zp[i] + zp[16 + i] + zp[32 + i] + zp[48 + i];
        if (z == 0.f) z = 1.f;
        float r = ssum / z;
        out[((size_t)(b * 2048 + i0 + i)) * 64 + o] = r > 0.f ? r : expm1f(r);
    }
}

extern "C" void kernel_launch(void* const* d_in, const int* in_sizes, int n_in,
                              void* d_out, int out_size, void* d_ws, size_t ws_size,
                              hipStream_t stream) {
    const float* h   = (const float*)d_in[0];
    const int*   adj = (const int*)d_in[1];
    const float* W   = (const float*)d_in[2];
    const float* a   = (const float*)d_in[3];
    float* out = (float*)d_out;

    unsigned short* whT = (unsigned short*)d_ws;                         // 2 MiB
    float* sw  = (float*)((char*)d_ws + 2097152);                        // 64 KiB
    float* tw  = (float*)((char*)d_ws + 2097152 + 65536);                // 64 KiB
    unsigned* mask = (unsigned*)((char*)d_ws + 2097152 + 131072);        // 4 MiB

    hipLaunchKernelGGL(k01, dim3(1280), dim3(256), 0, stream, h, adj, W, a, whT, sw, tw, mask);
    hipLaunchKernelGGL(k2_attn, dim3(1024), dim3(256), 0, stream, mask, whT, sw, tw, out);
}

// Round 3
// 232.976 us; speedup vs baseline: 1.0134x; 1.0134x over previous
//
#include <hip/hip_runtime.h>

// GAT layer: B=8, N=2048, Fin=Fout=64
// k01: blocks 0..255    = k1: Wh=h@W (MFMA bf16 -> WhT[b][o][n]) + s,t fp32 via Wa=W@a
//      blocks 256..1279 = k0: pack adj!=0 into bitmask bytes (134 MB -> 4 MB), pure stream
// k2 : masked softmax + P@Wh; mask in VGPRs, t in LDS, whT from L2.
//      Spill-proof: no double-buffer, no local arrays, launch_bounds(256,2) = 256-VGPR cap.

#define ALPHA 0.2f

typedef __attribute__((ext_vector_type(8))) short  short8;
typedef __attribute__((ext_vector_type(4))) float  f32x4;

static __device__ __forceinline__ unsigned short f2bf(float f) {
    unsigned u = __builtin_bit_cast(unsigned, f);
    u += 0x7fffu + ((u >> 16) & 1u);   // round-to-nearest-even
    return (unsigned short)(u >> 16);
}

// two f32 -> packed bf16x2 (round-half-up via +0x8000, v_perm grabs high halves)
static __device__ __forceinline__ unsigned pack_bf2(float lo, float hi) {
    unsigned ulo = __builtin_bit_cast(unsigned, lo) + 0x8000u;
    unsigned uhi = __builtin_bit_cast(unsigned, hi) + 0x8000u;
    return __builtin_amdgcn_perm(uhi, ulo, 0x07060302);
}

// ---------------- k01 ----------------
__global__ __launch_bounds__(256) void k01(
    const float* __restrict__ h, const int* __restrict__ adj,
    const float* __restrict__ W, const float* __restrict__ a,
    unsigned short* __restrict__ whT, float* __restrict__ sw,
    float* __restrict__ tw, unsigned char* __restrict__ mask)
{
    __shared__ float W_l[64 * 65];
    __shared__ float wa[128];
    __shared__ float tile[4 * 16 * 65];

    const int tid = threadIdx.x;

    if (blockIdx.x >= 256) {
        // ---- k0: adj -> bitmask bytes; byte p covers j = p*8..p*8+7 ----
        const int mb = blockIdx.x - 256;          // 0..1023
        const int4* a4 = (const int4*)adj;        // 8,388,608 int4 total
        #pragma unroll 1
        for (int g0 = 0; g0 < 16; g0 += 4) {
            int4 v0a, v0b, v1a, v1b, v2a, v2b, v3a, v3b;
            const size_t p0 = (size_t)mb * 4096 + (size_t)g0 * 256 + tid;
            v0a = a4[p0 * 2];          v0b = a4[p0 * 2 + 1];
            v1a = a4[(p0 + 256) * 2];  v1b = a4[(p0 + 256) * 2 + 1];
            v2a = a4[(p0 + 512) * 2];  v2b = a4[(p0 + 512) * 2 + 1];
            v3a = a4[(p0 + 768) * 2];  v3b = a4[(p0 + 768) * 2 + 1];
            unsigned b0 = (v0a.x ? 1u:0u)|(v0a.y ? 2u:0u)|(v0a.z ? 4u:0u)|(v0a.w ? 8u:0u)
                        | (v0b.x ?16u:0u)|(v0b.y ?32u:0u)|(v0b.z ?64u:0u)|(v0b.w ?128u:0u);
            unsigned b1 = (v1a.x ? 1u:0u)|(v1a.y ? 2u:0u)|(v1a.z ? 4u:0u)|(v1a.w ? 8u:0u)
                        | (v1b.x ?16u:0u)|(v1b.y ?32u:0u)|(v1b.z ?64u:0u)|(v1b.w ?128u:0u);
            unsigned b2 = (v2a.x ? 1u:0u)|(v2a.y ? 2u:0u)|(v2a.z ? 4u:0u)|(v2a.w ? 8u:0u)
                        | (v2b.x ?16u:0u)|(v2b.y ?32u:0u)|(v2b.z ?64u:0u)|(v2b.w ?128u:0u);
            unsigned b3 = (v3a.x ? 1u:0u)|(v3a.y ? 2u:0u)|(v3a.z ? 4u:0u)|(v3a.w ? 8u:0u)
                        | (v3b.x ?16u:0u)|(v3b.y ?32u:0u)|(v3b.z ?64u:0u)|(v3b.w ?128u:0u);
            mask[p0]       = (unsigned char)b0;
            mask[p0 + 256] = (unsigned char)b1;
            mask[p0 + 512] = (unsigned char)b2;
            mask[p0 + 768] = (unsigned char)b3;
        }
        return;
    }

    // ---- k1: Wh + s,t ----
    const int lane = tid & 63, wv = tid >> 6;
    const int im   = lane & 15, kq = lane >> 4;

    #pragma unroll
    for (int k = 0; k < 16; ++k) {
        int e = tid + 256 * k;
        W_l[(e >> 6) * 65 + (e & 63)] = W[e];
    }
    __syncthreads();

    if (tid < 128) {
        int f = tid & 63;
        const float* ap = a + (tid >> 6) * 64;
        float acc = 0.f;
        #pragma unroll 8
        for (int o = 0; o < 64; ++o) acc += W_l[f * 65 + o] * ap[o];
        wa[tid] = acc;
    }
    __syncthreads();

    short8 bf[4][2];
    #pragma unroll
    for (int nb = 0; nb < 4; ++nb)
        #pragma unroll
        for (int ks = 0; ks < 2; ++ks)
            #pragma unroll
            for (int u = 0; u < 8; ++u)
                bf[nb][ks][u] = (short)f2bf(W_l[(ks * 32 + kq * 8 + u) * 65 + nb * 16 + im]);

    const int row0 = blockIdx.x * 64 + wv * 16;
    const int bb = row0 >> 11, n_base = row0 & 2047;
    const float* hrow = h + (size_t)(row0 + im) * 64;

    float hv[2][8];
    short8 af[2];
    float sp = 0.f, tp = 0.f;
    #pragma unroll
    for (int ks = 0; ks < 2; ++ks) {
        float4 A = *(const float4*)(hrow + ks * 32 + kq * 8);
        float4 Bv = *(const float4*)(hrow + ks * 32 + kq * 8 + 4);
        hv[ks][0] = A.x;  hv[ks][1] = A.y;  hv[ks][2] = A.z;  hv[ks][3] = A.w;
        hv[ks][4] = Bv.x; hv[ks][5] = Bv.y; hv[ks][6] = Bv.z; hv[ks][7] = Bv.w;
        #pragma unroll
        for (int u = 0; u < 8; ++u) {
            int f = ks * 32 + kq * 8 + u;
            sp += hv[ks][u] * wa[f];
            tp += hv[ks][u] * wa[64 + f];
            af[ks][u] = (short)f2bf(hv[ks][u]);
        }
    }
    sp += __shfl_xor(sp, 16, 64); sp += __shfl_xor(sp, 32, 64);
    tp += __shfl_xor(tp, 16, 64); tp += __shfl_xor(tp, 32, 64);
    if (lane < 16) {
        sw[row0 + lane] = sp;
        tw[row0 + lane] = tp;
    }

    f32x4 acc[4] = {{0.f,0.f,0.f,0.f},{0.f,0.f,0.f,0.f},{0.f,0.f,0.f,0.f},{0.f,0.f,0.f,0.f}};
    #pragma unroll
    for (int ks = 0; ks < 2; ++ks)
        #pragma unroll
        for (int nb = 0; nb < 4; ++nb)
            acc[nb] = __builtin_amdgcn_mfma_f32_16x16x32_bf16(af[ks], bf[nb][ks], acc[nb], 0, 0, 0);

    #pragma unroll
    for (int nb = 0; nb < 4; ++nb)
        #pragma unroll
        for (int r = 0; r < 4; ++r)
            tile[wv * 1040 + (kq * 4 + r) * 65 + nb * 16 + im] = acc[nb][r];
    __syncthreads();

    #pragma unroll
    for (int k = 0; k < 16; ++k) {
        int o = kq + 4 * k;
        float v = tile[wv * 1040 + im * 65 + o];
        whT[(size_t)(bb * 64 + o) * 2048 + n_base + im] = f2bf(v);
    }
}

// ---------------- k2: masked softmax + P@Wh ----------------
// grid 1024 (b, i0) x 256 thr; wave = 512-j stripe; only 4 L2 loads + 2 LDS reads per iter.
__global__ __launch_bounds__(256, 2) void k2_attn(
    const unsigned* __restrict__ mask, const unsigned short* __restrict__ whT,
    const float* __restrict__ sw, const float* __restrict__ tw,
    float* __restrict__ out)
{
    __shared__ float t_l[2048];
    __shared__ float cpart[4 * 1040];
    __shared__ float zp[64];

    const int tid  = threadIdx.x;
    const int lane = tid & 63, wv = tid >> 6;
    const int im   = lane & 15, kq = lane >> 4;
    const int b    = blockIdx.x >> 7;
    const int i0   = (blockIdx.x & 127) << 4;

    // stage t row -> LDS
    {
        const float4* tp4 = (const float4*)(tw + (size_t)b * 2048);
        *(float4*)&t_l[tid * 4]         = tp4[tid];
        *(float4*)&t_l[(tid + 256) * 4] = tp4[tid + 256];
    }

    // preload this lane's 16 mask words (row i0+im, j in [wv*512, wv*512+512))
    const uint4* mrow4 = (const uint4*)(mask + (size_t)(b * 2048 + i0 + im) * 64 + wv * 16);
    const uint4 mA = mrow4[0], mB = mrow4[1], mC = mrow4[2], mD = mrow4[3];
    const unsigned mm[16] = {mA.x, mA.y, mA.z, mA.w, mB.x, mB.y, mB.z, mB.w,
                             mC.x, mC.y, mC.z, mC.w, mD.x, mD.y, mD.z, mD.w};

    const float sl = sw[b * 2048 + i0 + im];
    const int j00 = wv * 512 + kq * 8;
    const unsigned short* whp0 = whT + ((size_t)(b * 64 +  0 + im) * 2048 + j00);
    const unsigned short* whp1 = whT + ((size_t)(b * 64 + 16 + im) * 2048 + j00);
    const unsigned short* whp2 = whT + ((size_t)(b * 64 + 32 + im) * 2048 + j00);
    const unsigned short* whp3 = whT + ((size_t)(b * 64 + 48 + im) * 2048 + j00);

    __syncthreads();

    f32x4 acc0 = {0.f,0.f,0.f,0.f}, acc1 = {0.f,0.f,0.f,0.f};
    f32x4 acc2 = {0.f,0.f,0.f,0.f}, acc3 = {0.f,0.f,0.f,0.f};
    float zs = 0.f;

    #pragma unroll
    for (int s = 0; s < 16; ++s) {
        const short8 w0 = *(const short8*)(const void*)(whp0 + s * 32);
        const short8 w1 = *(const short8*)(const void*)(whp1 + s * 32);
        const short8 w2 = *(const short8*)(const void*)(whp2 + s * 32);
        const short8 w3 = *(const short8*)(const void*)(whp3 + s * 32);

        const float4 tA = *(const float4*)&t_l[j00 + s * 32];
        const float4 tB = *(const float4*)&t_l[j00 + s * 32 + 4];
        const unsigned mbyte = (mm[s] >> (kq * 8)) & 0xffu;

        float e0 = sl + tA.x; e0 = fmaxf(e0, ALPHA * e0);
        float e1 = sl + tA.y; e1 = fmaxf(e1, ALPHA * e1);
        float e2 = sl + tA.z; e2 = fmaxf(e2, ALPHA * e2);
        float e3 = sl + tA.w; e3 = fmaxf(e3, ALPHA * e3);
        float e4 = sl + tB.x; e4 = fmaxf(e4, ALPHA * e4);
        float e5 = sl + tB.y; e5 = fmaxf(e5, ALPHA * e5);
        float e6 = sl + tB.z; e6 = fmaxf(e6, ALPHA * e6);
        float e7 = sl + tB.w; e7 = fmaxf(e7, ALPHA * e7);

        float p0 = (mbyte &   1u) ? __expf(e0) : 0.f;
        float p1 = (mbyte &   2u) ? __expf(e1) : 0.f;
        float p2 = (mbyte &   4u) ? __expf(e2) : 0.f;
        float p3 = (mbyte &   8u) ? __expf(e3) : 0.f;
        float p4 = (mbyte &  16u) ? __expf(e4) : 0.f;
        float p5 = (mbyte &  32u) ? __expf(e5) : 0.f;
        float p6 = (mbyte &  64u) ? __expf(e6) : 0.f;
        float p7 = (mbyte & 128u) ? __expf(e7) : 0.f;

        zs += ((p0 + p1) + (p2 + p3)) + ((p4 + p5) + (p6 + p7));

        int4 ai;
        ai.x = (int)pack_bf2(p0, p1);
        ai.y = (int)pack_bf2(p2, p3);
        ai.z = (int)pack_bf2(p4, p5);
        ai.w = (int)pack_bf2(p6, p7);
        const short8 af = __builtin_bit_cast(short8, ai);

        acc0 = __builtin_amdgcn_mfma_f32_16x16x32_bf16(af, w0, acc0, 0, 0, 0);
        acc1 = __builtin_amdgcn_mfma_f32_16x16x32_bf16(af, w1, acc1, 0, 0, 0);
        acc2 = __builtin_amdgcn_mfma_f32_16x16x32_bf16(af, w2, acc2, 0, 0, 0);
        acc3 = __builtin_amdgcn_mfma_f32_16x16x32_bf16(af, w3, acc3, 0, 0, 0);
    }

    zs += __shfl_xor(zs, 16, 64);
    zs += __shfl_xor(zs, 32, 64);
    if (lane < 16) zp[wv * 16 + lane] = zs;

    #pragma unroll
    for (int r = 0; r < 4; ++r) {
        cpart[wv * 1040 + (kq * 4 + r) * 65 +  0 + im] = acc0[r];
        cpart[wv * 1040 + (kq * 4 + r) * 65 + 16 + im] = acc1[r];
        cpart[wv * 1040 + (kq * 4 + r) * 65 + 32 + im] = acc2[r];
        cpart[wv * 1040 + (kq * 4 + r) * 65 + 48 + im] = acc3[r];
    }
    __syncthreads();

    #pragma unroll
    for (int k = 0; k < 4; ++k) {
        int idx = tid + 256 * k;
        int i = idx >> 6, o = idx & 63;
        float ssum = cpart[0 * 1040 + i * 65 + o] + cpart[1 * 1040 + i * 65 + o]
                   + cpart[2 * 1040 + i * 65 + o] + cpart[3 * 1040 + i * 65 + o];
        float z = zp[i] + zp[16 + i] + zp[32 + i] + zp[48 + i];
        if (z == 0.f) z = 1.f;
        float r = ssum / z;
        out[((size_t)(b * 2048 + i0 + i)) * 64 + o] = r > 0.f ? r : expm1f(r);
    }
}

extern "C" void kernel_launch(void* const* d_in, const int* in_sizes, int n_in,
                              void* d_out, int out_size, void* d_ws, size_t ws_size,
                              hipStream_t stream) {
    const float* h   = (const float*)d_in[0];
    const int*   adj = (const int*)d_in[1];
    const float* W   = (const float*)d_in[2];
    const float* a   = (const float*)d_in[3];
    float* out = (float*)d_out;

    unsigned short* whT = (unsigned short*)d_ws;                         // 2 MiB
    float* sw  = (float*)((char*)d_ws + 2097152);                        // 64 KiB
    float* tw  = (float*)((char*)d_ws + 2097152 + 65536);                // 64 KiB
    unsigned char* mask = (unsigned char*)((char*)d_ws + 2097152 + 131072); // 4 MiB

    hipLaunchKernelGGL(k01, dim3(1280), dim3(256), 0, stream, h, adj, W, a, whT, sw, tw, mask);
    hipLaunchKernelGGL(k2_attn, dim3(1024), dim3(256), 0, stream,
                       (const unsigned*)mask, whT, sw, tw, out);
}

// Round 4
// 214.947 us; speedup vs baseline: 1.0984x; 1.0839x over previous
//
#include <hip/hip_runtime.h>

// GAT layer: B=8, N=2048, Fin=Fout=64
// k01: blocks 0..255    = k1: Wh=h@W (MFMA) stored in MFMA-B-fragment order (whF) + s,t fp32
//      blocks 256..1279 = k0: pack adj!=0 into bitmask bytes (134 MB -> 4 MB), pure stream
// k2 : masked softmax + P@Wh. No exp in j-loop (A*B>1 factorization); whF loads are
//      1 KB contiguous per wave (fragment layout); mask in VGPRs; exp-tables in LDS.

#define ALPHA 0.2f

typedef __attribute__((ext_vector_type(8))) short  short8;
typedef __attribute__((ext_vector_type(4))) float  f32x4;

static __device__ __forceinline__ unsigned short f2bf(float f) {
    unsigned u = __builtin_bit_cast(unsigned, f);
    u += 0x7fffu + ((u >> 16) & 1u);   // round-to-nearest-even
    return (unsigned short)(u >> 16);
}

// two f32 -> packed bf16x2 (lo in low half), round-half-up
static __device__ __forceinline__ unsigned pack_bf2(float lo, float hi) {
    unsigned ulo = __builtin_bit_cast(unsigned, lo) + 0x8000u;
    unsigned uhi = __builtin_bit_cast(unsigned, hi) + 0x8000u;
    return __builtin_amdgcn_perm(uhi, ulo, 0x07060302);
}

// ---------------- k01 ----------------
__global__ __launch_bounds__(256) void k01(
    const float* __restrict__ h, const int* __restrict__ adj,
    const float* __restrict__ W, const float* __restrict__ a,
    uint4* __restrict__ whF, float* __restrict__ sw,
    float* __restrict__ tw, unsigned char* __restrict__ mask)
{
    __shared__ float W_l[64 * 65];
    __shared__ float wa[128];
    __shared__ float tile[4 * 16 * 65];

    const int tid = threadIdx.x;

    if (blockIdx.x >= 256) {
        // ---- k0: adj -> bitmask bytes; byte p covers j = p*8..p*8+7 ----
        const int mb = blockIdx.x - 256;          // 0..1023
        const int4* a4 = (const int4*)adj;
        #pragma unroll 1
        for (int g0 = 0; g0 < 16; g0 += 4) {
            int4 v0a, v0b, v1a, v1b, v2a, v2b, v3a, v3b;
            const size_t p0 = (size_t)mb * 4096 + (size_t)g0 * 256 + tid;
            v0a = a4[p0 * 2];          v0b = a4[p0 * 2 + 1];
            v1a = a4[(p0 + 256) * 2];  v1b = a4[(p0 + 256) * 2 + 1];
            v2a = a4[(p0 + 512) * 2];  v2b = a4[(p0 + 512) * 2 + 1];
            v3a = a4[(p0 + 768) * 2];  v3b = a4[(p0 + 768) * 2 + 1];
            unsigned b0 = (v0a.x ? 1u:0u)|(v0a.y ? 2u:0u)|(v0a.z ? 4u:0u)|(v0a.w ? 8u:0u)
                        | (v0b.x ?16u:0u)|(v0b.y ?32u:0u)|(v0b.z ?64u:0u)|(v0b.w ?128u:0u);
            unsigned b1 = (v1a.x ? 1u:0u)|(v1a.y ? 2u:0u)|(v1a.z ? 4u:0u)|(v1a.w ? 8u:0u)
                        | (v1b.x ?16u:0u)|(v1b.y ?32u:0u)|(v1b.z ?64u:0u)|(v1b.w ?128u:0u);
            unsigned b2 = (v2a.x ? 1u:0u)|(v2a.y ? 2u:0u)|(v2a.z ? 4u:0u)|(v2a.w ? 8u:0u)
                        | (v2b.x ?16u:0u)|(v2b.y ?32u:0u)|(v2b.z ?64u:0u)|(v2b.w ?128u:0u);
            unsigned b3 = (v3a.x ? 1u:0u)|(v3a.y ? 2u:0u)|(v3a.z ? 4u:0u)|(v3a.w ? 8u:0u)
                        | (v3b.x ?16u:0u)|(v3b.y ?32u:0u)|(v3b.z ?64u:0u)|(v3b.w ?128u:0u);
            mask[p0]       = (unsigned char)b0;
            mask[p0 + 256] = (unsigned char)b1;
            mask[p0 + 512] = (unsigned char)b2;
            mask[p0 + 768] = (unsigned char)b3;
        }
        return;
    }

    // ---- k1: Wh + s,t ----
    const int lane = tid & 63, wv = tid >> 6;
    const int im   = lane & 15, kq = lane >> 4;

    #pragma unroll
    for (int k = 0; k < 16; ++k) {
        int e = tid + 256 * k;
        W_l[(e >> 6) * 65 + (e & 63)] = W[e];
    }
    __syncthreads();

    if (tid < 128) {
        int f = tid & 63;
        const float* ap = a + (tid >> 6) * 64;
        float acc = 0.f;
        #pragma unroll 8
        for (int o = 0; o < 64; ++o) acc += W_l[f * 65 + o] * ap[o];
        wa[tid] = acc;
    }
    __syncthreads();

    short8 bf[4][2];
    #pragma unroll
    for (int nb = 0; nb < 4; ++nb)
        #pragma unroll
        for (int ks = 0; ks < 2; ++ks)
            #pragma unroll
            for (int u = 0; u < 8; ++u)
                bf[nb][ks][u] = (short)f2bf(W_l[(ks * 32 + kq * 8 + u) * 65 + nb * 16 + im]);

    const int row0 = blockIdx.x * 64 + wv * 16;
    const float* hrow = h + (size_t)(row0 + im) * 64;

    float hv[2][8];
    short8 af[2];
    float sp = 0.f, tp = 0.f;
    #pragma unroll
    for (int ks = 0; ks < 2; ++ks) {
        float4 A = *(const float4*)(hrow + ks * 32 + kq * 8);
        float4 Bv = *(const float4*)(hrow + ks * 32 + kq * 8 + 4);
        hv[ks][0] = A.x;  hv[ks][1] = A.y;  hv[ks][2] = A.z;  hv[ks][3] = A.w;
        hv[ks][4] = Bv.x; hv[ks][5] = Bv.y; hv[ks][6] = Bv.z; hv[ks][7] = Bv.w;
        #pragma unroll
        for (int u = 0; u < 8; ++u) {
            int f = ks * 32 + kq * 8 + u;
            sp += hv[ks][u] * wa[f];
            tp += hv[ks][u] * wa[64 + f];
            af[ks][u] = (short)f2bf(hv[ks][u]);
        }
    }
    sp += __shfl_xor(sp, 16, 64); sp += __shfl_xor(sp, 32, 64);
    tp += __shfl_xor(tp, 16, 64); tp += __shfl_xor(tp, 32, 64);
    if (lane < 16) {
        sw[row0 + lane] = sp;
        tw[row0 + lane] = tp;
    }

    f32x4 acc[4] = {{0.f,0.f,0.f,0.f},{0.f,0.f,0.f,0.f},{0.f,0.f,0.f,0.f},{0.f,0.f,0.f,0.f}};
    #pragma unroll
    for (int ks = 0; ks < 2; ++ks)
        #pragma unroll
        for (int nb = 0; nb < 4; ++nb)
            acc[nb] = __builtin_amdgcn_mfma_f32_16x16x32_bf16(af[ks], bf[nb][ks], acc[nb], 0, 0, 0);

    #pragma unroll
    for (int nb = 0; nb < 4; ++nb)
        #pragma unroll
        for (int r = 0; r < 4; ++r)
            tile[wv * 1040 + (kq * 4 + r) * 65 + nb * 16 + im] = acc[nb][r];
    __syncthreads();

    // ---- store Wh in MFMA-B-fragment order ----
    // whF uint4 index: ((bb*64 + c)*4 + ot)*64 + lane ; lane holds
    // Wh[j = c*32 + (lane>>4)*8 + u][o = ot*16 + (lane&15)], u=0..7 packed bf16.
    {
        const int blk_row0 = blockIdx.x * 64;
        const int bb2 = blk_row0 >> 11;
        const int c_base = (blk_row0 & 2047) >> 5;
        #pragma unroll
        for (int k = 0; k < 2; ++k) {
            int e = tid + 256 * k;
            int l = e & 63, ot = (e >> 6) & 3, cl_ = e >> 8;
            int o = ot * 16 + (l & 15);
            int jb = cl_ * 32 + (l >> 4) * 8;
            unsigned d0, d1, d2, d3;
            {
                int j0 = jb;
                d0 = pack_bf2(tile[(j0 >> 4) * 1040 + (j0 & 15) * 65 + o],
                              tile[(j0 >> 4) * 1040 + ((j0 & 15) + 1) * 65 + o]);
                j0 = jb + 2;
                d1 = pack_bf2(tile[(j0 >> 4) * 1040 + (j0 & 15) * 65 + o],
                              tile[(j0 >> 4) * 1040 + ((j0 & 15) + 1) * 65 + o]);
                j0 = jb + 4;
                d2 = pack_bf2(tile[(j0 >> 4) * 1040 + (j0 & 15) * 65 + o],
                              tile[(j0 >> 4) * 1040 + ((j0 & 15) + 1) * 65 + o]);
                j0 = jb + 6;
                d3 = pack_bf2(tile[(j0 >> 4) * 1040 + (j0 & 15) * 65 + o],
                              tile[(j0 >> 4) * 1040 + ((j0 & 15) + 1) * 65 + o]);
            }
            uint4 val = {d0, d1, d2, d3};
            whF[(size_t)(((bb2 * 64 + c_base + cl_) * 4 + ot)) * 64 + l] = val;
        }
    }
}

// ---------------- k2: masked softmax + P@Wh ----------------
// grid 1024 (b, i0) x 256 thr; wave = 512-j stripe.
// p = adj ? ( A_i*B_j > 1 ? A_i*B_j : C_i*D_j ) : 0   (== adj ? exp(lrelu(s+t)) : 0)
__global__ __launch_bounds__(256, 2) void k2_attn(
    const unsigned* __restrict__ mask, const uint4* __restrict__ whF,
    const float* __restrict__ sw, const float* __restrict__ tw,
    float* __restrict__ out)
{
    __shared__ float eB[2048];
    __shared__ float eD[2048];
    __shared__ float cpart[4 * 1040];
    __shared__ float zp[64];

    const int tid  = threadIdx.x;
    const int lane = tid & 63, wv = tid >> 6;
    const int im   = lane & 15, kq = lane >> 4;
    const int b    = blockIdx.x >> 7;
    const int i0   = (blockIdx.x & 127) << 4;

    // exp tables: eB[j]=exp(t_j), eD[j]=exp(ALPHA*t_j)
    {
        const float4* tp4 = (const float4*)(tw + (size_t)b * 2048);
        float4 t0 = tp4[tid], t1 = tp4[tid + 256];
        float4 e0 = {__expf(t0.x), __expf(t0.y), __expf(t0.z), __expf(t0.w)};
        float4 e1 = {__expf(t1.x), __expf(t1.y), __expf(t1.z), __expf(t1.w)};
        float4 f0 = {__expf(ALPHA*t0.x), __expf(ALPHA*t0.y), __expf(ALPHA*t0.z), __expf(ALPHA*t0.w)};
        float4 f1 = {__expf(ALPHA*t1.x), __expf(ALPHA*t1.y), __expf(ALPHA*t1.z), __expf(ALPHA*t1.w)};
        *(float4*)&eB[tid * 4] = e0;  *(float4*)&eB[(tid + 256) * 4] = e1;
        *(float4*)&eD[tid * 4] = f0;  *(float4*)&eD[(tid + 256) * 4] = f1;
    }

    // mask preload: 16 words/lane (row i0+im, j in [wv*512, wv*512+512))
    const uint4* mrow4 = (const uint4*)(mask + (size_t)(b * 2048 + i0 + im) * 64 + wv * 16);
    const uint4 mA = mrow4[0], mB = mrow4[1], mC = mrow4[2], mD = mrow4[3];
    const unsigned mm[16] = {mA.x, mA.y, mA.z, mA.w, mB.x, mB.y, mB.z, mB.w,
                             mC.x, mC.y, mC.z, mC.w, mD.x, mD.y, mD.z, mD.w};

    const float sl = sw[b * 2048 + i0 + im];
    const float al = __expf(sl), cl_ = __expf(ALPHA * sl);
    const int j00 = wv * 512 + kq * 8;
    const uint4* wbase = whF + (size_t)((b * 64 + wv * 16) * 4) * 64 + lane;

    __syncthreads();

    f32x4 acc0 = {0.f,0.f,0.f,0.f}, acc1 = {0.f,0.f,0.f,0.f};
    f32x4 acc2 = {0.f,0.f,0.f,0.f}, acc3 = {0.f,0.f,0.f,0.f};
    float zs = 0.f;

    #pragma unroll
    for (int s = 0; s < 16; ++s) {
        const uint4 w0 = wbase[(s * 4 + 0) * 64];
        const uint4 w1 = wbase[(s * 4 + 1) * 64];
        const uint4 w2 = wbase[(s * 4 + 2) * 64];
        const uint4 w3 = wbase[(s * 4 + 3) * 64];

        const float4 bA = *(const float4*)&eB[j00 + s * 32];
        const float4 bBv = *(const float4*)&eB[j00 + s * 32 + 4];
        const float4 dA = *(const float4*)&eD[j00 + s * 32];
        const float4 dBv = *(const float4*)&eD[j00 + s * 32 + 4];
        const unsigned mbyte = (mm[s] >> (kq * 8)) & 0xffu;

        float m0 = al * bA.x, n0 = cl_ * dA.x;
        float m1 = al * bA.y, n1 = cl_ * dA.y;
        float m2 = al * bA.z, n2 = cl_ * dA.z;
        float m3 = al * bA.w, n3 = cl_ * dA.w;
        float m4 = al * bBv.x, n4 = cl_ * dBv.x;
        float m5 = al * bBv.y, n5 = cl_ * dBv.y;
        float m6 = al * bBv.z, n6 = cl_ * dBv.z;
        float m7 = al * bBv.w, n7 = cl_ * dBv.w;

        float p0 = m0 > 1.f ? m0 : n0;  p0 = (mbyte &   1u) ? p0 : 0.f;
        float p1 = m1 > 1.f ? m1 : n1;  p1 = (mbyte &   2u) ? p1 : 0.f;
        float p2 = m2 > 1.f ? m2 : n2;  p2 = (mbyte &   4u) ? p2 : 0.f;
        float p3 = m3 > 1.f ? m3 : n3;  p3 = (mbyte &   8u) ? p3 : 0.f;
        float p4 = m4 > 1.f ? m4 : n4;  p4 = (mbyte &  16u) ? p4 : 0.f;
        float p5 = m5 > 1.f ? m5 : n5;  p5 = (mbyte &  32u) ? p5 : 0.f;
        float p6 = m6 > 1.f ? m6 : n6;  p6 = (mbyte &  64u) ? p6 : 0.f;
        float p7 = m7 > 1.f ? m7 : n7;  p7 = (mbyte & 128u) ? p7 : 0.f;

        zs += ((p0 + p1) + (p2 + p3)) + ((p4 + p5) + (p6 + p7));

        int4 ai;
        ai.x = (int)pack_bf2(p0, p1);
        ai.y = (int)pack_bf2(p2, p3);
        ai.z = (int)pack_bf2(p4, p5);
        ai.w = (int)pack_bf2(p6, p7);
        const short8 af = __builtin_bit_cast(short8, ai);

        acc0 = __builtin_amdgcn_mfma_f32_16x16x32_bf16(af, __builtin_bit_cast(short8, w0), acc0, 0, 0, 0);
        acc1 = __builtin_amdgcn_mfma_f32_16x16x32_bf16(af, __builtin_bit_cast(short8, w1), acc1, 0, 0, 0);
        acc2 = __builtin_amdgcn_mfma_f32_16x16x32_bf16(af, __builtin_bit_cast(short8, w2), acc2, 0, 0, 0);
        acc3 = __builtin_amdgcn_mfma_f32_16x16x32_bf16(af, __builtin_bit_cast(short8, w3), acc3, 0, 0, 0);
    }

    zs += __shfl_xor(zs, 16, 64);
    zs += __shfl_xor(zs, 32, 64);
    if (lane < 16) zp[wv * 16 + lane] = zs;

    #pragma unroll
    for (int r = 0; r < 4; ++r) {
        cpart[wv * 1040 + (kq * 4 + r) * 65 +  0 + im] = acc0[r];
        cpart[wv * 1040 + (kq * 4 + r) * 65 + 16 + im] = acc1[r];
        cpart[wv * 1040 + (kq * 4 + r) * 65 + 32 + im] = acc2[r];
        cpart[wv * 1040 + (kq * 4 + r) * 65 + 48 + im] = acc3[r];
    }
    __syncthreads();

    #pragma unroll
    for (int k = 0; k < 4; ++k) {
        int idx = tid + 256 * k;
        int i = idx >> 6, o = idx & 63;
        float ssum = cpart[0 * 1040 + i * 65 + o] + cpart[1 * 1040 + i * 65 + o]
                   + cpart[2 * 1040 + i * 65 + o] + cpart[3 * 1040 + i * 65 + o];
        float z = zp[i] + zp[16 + i] + zp[32 + i] + zp[48 + i];
        if (z == 0.f) z = 1.f;
        float r = ssum / z;
        out[((size_t)(b * 2048 + i0 + i)) * 64 + o] = r > 0.f ? r : expm1f(r);
    }
}

extern "C" void kernel_launch(void* const* d_in, const int* in_sizes, int n_in,
                              void* d_out, int out_size, void* d_ws, size_t ws_size,
                              hipStream_t stream) {
    const float* h   = (const float*)d_in[0];
    const int*   adj = (const int*)d_in[1];
    const float* W   = (const float*)d_in[2];
    const float* a   = (const float*)d_in[3];
    float* out = (float*)d_out;

    uint4* whF = (uint4*)d_ws;                                           // 2 MiB
    float* sw  = (float*)((char*)d_ws + 2097152);                        // 64 KiB
    float* tw  = (float*)((char*)d_ws + 2097152 + 65536);                // 64 KiB
    unsigned char* mask = (unsigned char*)((char*)d_ws + 2097152 + 131072); // 4 MiB

    hipLaunchKernelGGL(k01, dim3(1280), dim3(256), 0, stream, h, adj, W, a, whF, sw, tw, mask);
    hipLaunchKernelGGL(k2_attn, dim3(1024), dim3(256), 0, stream,
                       (const unsigned*)mask, whF, sw, tw, out);
}